// Round 2
// baseline (618.730 us; speedup 1.0000x reference)
//
#include <hip/hip_runtime.h>
#include <hip/hip_bf16.h>
#include <stdint.h>

#define BB 2
#define SS 2048
#define DD 1024
#define HH 8
#define HD 128
#define TOPK 32
#define ROWS (BB*HH*SS)   // 32768

// ---------------------------------------------------------------- K1: top-32
__global__ __launch_bounds__(256) void topk_kernel(const float* __restrict__ aw,
                                                   int* __restrict__ idx_out) {
    const int row = blockIdx.x;
    const float* p = aw + (size_t)row * SS;
    const int t = threadIdx.x;
    float4 v0 = *(const float4*)(p + 4 * t);
    float4 v1 = *(const float4*)(p + 1024 + 4 * t);
    float vals[8] = {v0.x, v0.y, v0.z, v0.w, v1.x, v1.y, v1.z, v1.w};
    unsigned long long key[8];
#pragma unroll
    for (int i = 0; i < 8; i++) {
        int e = (i < 4) ? (4 * t + i) : (1024 + 4 * t + (i - 4));
        unsigned u = __float_as_uint(vals[i]);
        unsigned sk = (u & 0x80000000u) ? ~u : (u | 0x80000000u);
        key[i] = ((unsigned long long)sk << 11) | (unsigned)(2047 - e);
    }
    __shared__ int s_cnt;
    __shared__ int s_red[4];
    __shared__ unsigned long long s_cand[256];

    // threshold: N(0,1) quantile for ~80 survivors; bisect if out of range
    unsigned thr0 = __float_as_uint(1.76f) | 0x80000000u;
    unsigned long long T = ((unsigned long long)thr0 << 11) | 2047ull;
    unsigned long long lo = 0, hi = ~0ull;
    const int lane = t & 63, wv = t >> 6;
    for (int it = 0; it < 64; ++it) {
        int c = 0;
#pragma unroll
        for (int i = 0; i < 8; i++) c += (key[i] > T) ? 1 : 0;
        for (int off = 32; off; off >>= 1) c += __shfl_down(c, off, 64);
        if (lane == 0) s_red[wv] = c;
        __syncthreads();
        int tot = s_red[0] + s_red[1] + s_red[2] + s_red[3];
        if (tot >= 32 && tot <= 192) break;
        if (tot > 192) lo = T; else hi = T;
        T = lo + ((hi - lo) >> 1);
        __syncthreads();
    }
    if (t == 0) s_cnt = 0;
    __syncthreads();
#pragma unroll
    for (int i = 0; i < 8; i++) {
        if (key[i] > T) {
            int pos = atomicAdd(&s_cnt, 1);
            if (pos < 256) s_cand[pos] = key[i];
        }
    }
    __syncthreads();
    const int C = s_cnt < 256 ? s_cnt : 256;
    if (t < 64) {  // wave 0 does exact top-32 among candidates
        unsigned long long c0 = (t < C) ? s_cand[t] : 0ull;
        unsigned long long c1 = (t + 64 < C) ? s_cand[t + 64] : 0ull;
        unsigned long long c2 = (t + 128 < C) ? s_cand[t + 128] : 0ull;
        unsigned long long best = c0 > c1 ? c0 : c1; if (c2 > best) best = c2;
        int* orow = idx_out + (size_t)row * TOPK;
        for (int itr = 0; itr < TOPK; ++itr) {
            unsigned long long m = best;
#pragma unroll
            for (int off = 32; off; off >>= 1) {
                unsigned long long o = __shfl_xor(m, off, 64);
                if (o > m) m = o;
            }
            if (best == m && m != 0ull) {
                orow[itr] = 2047 - (int)(m & 2047ull);
                if (c0 == m) c0 = 0; else if (c1 == m) c1 = 0; else c2 = 0;
                best = c0 > c1 ? c0 : c1; if (c2 > best) best = c2;
            }
        }
    }
}

// ------------------------------------------------------- K2: softmax stats
// fp16 MFMA (not bf16): selected indices are independent of scores, so the
// eps*Z term usually dominates the renorm denominator; Z's relative error is a
// per-(head,row) output scale error that LN does NOT cancel. bf16 gave
// absmax 0.31; fp16's 3 extra mantissa bits cut it ~8x.
typedef float f32x4 __attribute__((ext_vector_type(4)));
typedef _Float16 f16x8 __attribute__((ext_vector_type(8)));
typedef _Float16 f16x4 __attribute__((ext_vector_type(4)));

#define KPAD 136   // 128 + 8 halves pad: breaks LDS bank conflicts, keeps 16B align

__global__ __launch_bounds__(256) void stats_kernel(const float* __restrict__ q,
                                                    const float* __restrict__ k,
                                                    float* __restrict__ ws_m,
                                                    float* __restrict__ ws_l) {
    __shared__ __align__(16) _Float16 Qs[128 * KPAD];
    __shared__ __align__(16) _Float16 Ks[128 * KPAD];
    const int blk = blockIdx.x;      // 256 blocks
    const int bh = blk >> 4;         // 0..15
    const int qt = blk & 15;
    const int b = bh >> 3, h = bh & 7;
    const int t = threadIdx.x;
    const int wv = t >> 6, lane = t & 63;
    const int l16 = lane & 15, quad = lane >> 4;

    // stage Q tile (rows qt*128..+128, head slice) as fp16
    const float* qbase = q + ((size_t)(b * SS + qt * 128) * DD + h * HD);
#pragma unroll
    for (int i = 0; i < 16; ++i) {
        int fi = t + 256 * i;            // float4 index
        int r = fi >> 5, c4 = fi & 31;
        float4 f = *(const float4*)(qbase + (size_t)r * DD + c4 * 4);
        *(f16x4*)&Qs[r * KPAD + c4 * 4] =
            (f16x4){(_Float16)f.x, (_Float16)f.y, (_Float16)f.z, (_Float16)f.w};
    }
    float mrun[2][4], lrun[2][4];
#pragma unroll
    for (int a = 0; a < 2; a++)
#pragma unroll
        for (int r2 = 0; r2 < 4; r2++) { mrun[a][r2] = -INFINITY; lrun[a][r2] = 0.f; }

    const float* kbase = k + ((size_t)(b * SS) * DD + h * HD);
    for (int kt = 0; kt < 16; ++kt) {
        __syncthreads();
#pragma unroll
        for (int i = 0; i < 16; ++i) {
            int fi = t + 256 * i;
            int r = fi >> 5, c4 = fi & 31;
            float4 f = *(const float4*)(kbase + (size_t)(kt * 128 + r) * DD + c4 * 4);
            *(f16x4*)&Ks[r * KPAD + c4 * 4] =
                (f16x4){(_Float16)f.x, (_Float16)f.y, (_Float16)f.z, (_Float16)f.w};
        }
        __syncthreads();
        f32x4 acc[2][8];
#pragma unroll
        for (int a = 0; a < 2; a++)
#pragma unroll
            for (int n = 0; n < 8; n++) acc[a][n] = (f32x4){0.f, 0.f, 0.f, 0.f};
#pragma unroll
        for (int ks = 0; ks < 4; ++ks) {
            f16x8 af[2], bfr[8];
#pragma unroll
            for (int a = 0; a < 2; a++)
                af[a] = *(const f16x8*)&Qs[(wv * 32 + a * 16 + l16) * KPAD + ks * 32 + quad * 8];
#pragma unroll
            for (int n = 0; n < 8; n++)
                bfr[n] = *(const f16x8*)&Ks[(n * 16 + l16) * KPAD + ks * 32 + quad * 8];
#pragma unroll
            for (int a = 0; a < 2; a++)
#pragma unroll
                for (int n = 0; n < 8; n++)
                    acc[a][n] = __builtin_amdgcn_mfma_f32_16x16x32_f16(af[a], bfr[n], acc[a][n], 0, 0, 0);
        }
        // online max / sumexp per row (row = wv*32 + a*16 + quad*4 + r2)
#pragma unroll
        for (int a = 0; a < 2; a++) {
#pragma unroll
            for (int r2 = 0; r2 < 4; r2++) {
                float tm = acc[a][0][r2];
#pragma unroll
                for (int n = 1; n < 8; n++) tm = fmaxf(tm, acc[a][n][r2]);
#pragma unroll
                for (int off = 1; off < 16; off <<= 1) tm = fmaxf(tm, __shfl_xor(tm, off, 64));
                float tl = 0.f;
#pragma unroll
                for (int n = 0; n < 8; n++) tl += __expf(acc[a][n][r2] - tm);
#pragma unroll
                for (int off = 1; off < 16; off <<= 1) tl += __shfl_xor(tl, off, 64);
                float mo = mrun[a][r2];
                float mn = fmaxf(mo, tm);
                lrun[a][r2] = lrun[a][r2] * __expf(mo - mn) + tl * __expf(tm - mn);
                mrun[a][r2] = mn;
            }
        }
    }
    if (l16 == 0) {
#pragma unroll
        for (int a = 0; a < 2; a++)
#pragma unroll
            for (int r2 = 0; r2 < 4; r2++) {
                int row = qt * 128 + wv * 32 + a * 16 + quad * 4 + r2;
                size_t g = (size_t)bh * SS + row;
                ws_m[g] = mrun[a][r2];
                ws_l[g] = lrun[a][r2];
            }
    }
}

// --------------------------------------------- K2b: gather scores + PV (fp32)
__global__ __launch_bounds__(128) void attnout_kernel(const float* __restrict__ q,
                                                      const float* __restrict__ k,
                                                      const float* __restrict__ v,
                                                      const int* __restrict__ idx_ws,
                                                      const float* __restrict__ ws_m,
                                                      const float* __restrict__ ws_l,
                                                      float* __restrict__ out) {
    const int R = blockIdx.x;            // 0..32767
    const int bh = R >> 11, s = R & 2047;
    const int b = bh >> 3, h = bh & 7;
    const int t = threadIdx.x;
    __shared__ float q_l[128];
    __shared__ int idx_l[32];
    __shared__ float e_l[32];
    __shared__ float w_l[32];
    const float* qrow = q + ((size_t)(b * SS + s) * DD + h * HD);
    q_l[t] = qrow[t];
    if (t < 32) idx_l[t] = idx_ws[(size_t)R * TOPK + t];
    __syncthreads();
    const float m = ws_m[R], Z = ws_l[R];
    const int l32 = t & 31, g = t >> 5;   // 4 groups of 32 lanes
    float4 q4 = *(const float4*)&q_l[l32 * 4];
    const float* kb = k + ((size_t)b * SS * DD + h * HD);
#pragma unroll
    for (int p = 0; p < 8; ++p) {
        int i = p * 4 + g;
        int ki = idx_l[i];
        float4 kv = *(const float4*)(kb + (size_t)ki * DD + l32 * 4);
        float d = q4.x * kv.x + q4.y * kv.y + q4.z * kv.z + q4.w * kv.w;
#pragma unroll
        for (int off = 1; off < 32; off <<= 1) d += __shfl_xor(d, off, 64);
        if (l32 == 0) e_l[i] = __expf(d - m);
    }
    __syncthreads();
    if (t < 32) {
        float e = e_l[t];
        float ssum = e;
#pragma unroll
        for (int off = 1; off < 32; off <<= 1) ssum += __shfl_xor(ssum, off, 64);
        float den = ssum + 1e-5f * Z;     // = S_sel + eps*Z  (exact renorm algebra)
        w_l[t] = e / den;
    }
    __syncthreads();
    const float* vb = v + ((size_t)b * SS * DD + h * HD);
    float accv = 0.f;
#pragma unroll 8
    for (int i = 0; i < 32; ++i) {
        accv += w_l[i] * vb[(size_t)idx_l[i] * DD + t];
    }
    out[((size_t)(b * SS + s) * DD) + h * HD + t] = accv;
}

// ----------------------------------------------------- K3: LayerNorm in-place
__global__ __launch_bounds__(256) void ln_kernel(float* __restrict__ out,
                                                 const float* __restrict__ gamma,
                                                 const float* __restrict__ beta) {
    const int row = blockIdx.x;   // B*S = 4096
    float* p = out + (size_t)row * DD;
    const int t = threadIdx.x;
    float x[4];
#pragma unroll
    for (int i = 0; i < 4; i++) x[i] = p[t + 256 * i];
    float sum = x[0] + x[1] + x[2] + x[3];
    __shared__ float red[4];
    const int lane = t & 63, wv = t >> 6;
    for (int off = 32; off; off >>= 1) sum += __shfl_down(sum, off, 64);
    if (lane == 0) red[wv] = sum;
    __syncthreads();
    float mean = (red[0] + red[1] + red[2] + red[3]) * (1.f / DD);
    __syncthreads();
    float vs = 0.f;
#pragma unroll
    for (int i = 0; i < 4; i++) { float d = x[i] - mean; vs += d * d; }
    for (int off = 32; off; off >>= 1) vs += __shfl_down(vs, off, 64);
    if (lane == 0) red[wv] = vs;
    __syncthreads();
    float var = (red[0] + red[1] + red[2] + red[3]) * (1.f / DD);
    float inv = rsqrtf(var + 1e-5f);
#pragma unroll
    for (int i = 0; i < 4; i++) {
        int c = t + 256 * i;
        p[c] = (x[i] - mean) * inv * gamma[c] + beta[c];
    }
}

extern "C" void kernel_launch(void* const* d_in, const int* in_sizes, int n_in,
                              void* d_out, int out_size, void* d_ws, size_t ws_size,
                              hipStream_t stream) {
    const float* q = (const float*)d_in[0];
    const float* k = (const float*)d_in[1];
    const float* v = (const float*)d_in[2];
    const float* aw = (const float*)d_in[3];
    const float* gamma = (const float*)d_in[4];
    const float* beta = (const float*)d_in[5];
    float* out = (float*)d_out;

    int* idx_ws = (int*)d_ws;
    float* ws_m = (float*)((char*)d_ws + (size_t)ROWS * TOPK * sizeof(int));
    float* ws_l = ws_m + ROWS;

    hipLaunchKernelGGL(topk_kernel, dim3(ROWS), dim3(256), 0, stream, aw, idx_ws);
    hipLaunchKernelGGL(stats_kernel, dim3(256), dim3(256), 0, stream, q, k, ws_m, ws_l);
    hipLaunchKernelGGL(attnout_kernel, dim3(ROWS), dim3(128), 0, stream, q, k, v, idx_ws, ws_m, ws_l, out);
    hipLaunchKernelGGL(ln_kernel, dim3(BB * SS), dim3(256), 0, stream, out, gamma, beta);
}

// Round 3
// 530.468 us; speedup vs baseline: 1.1664x; 1.1664x over previous
//
#include <hip/hip_runtime.h>
#include <hip/hip_bf16.h>
#include <stdint.h>

#define BB 2
#define SS 2048
#define DD 1024
#define HH 8
#define HD 128
#define TOPK 32
#define ROWS (BB*HH*SS)   // 32768

// ---------------------------------------------------------------- K1: top-32
// Fixed-threshold compaction + parallel rank selection (no serial argmax tail).
// Composite u64 key (sortable_value<<11 | (2047-idx)) == exact stable-argsort
// tie semantics of the reference.
__global__ __launch_bounds__(256) void topk_kernel(const float* __restrict__ aw,
                                                   int* __restrict__ idx_out) {
    const int row = blockIdx.x;
    const float* p = aw + (size_t)row * SS;
    const int t = threadIdx.x;
    float4 v0 = *(const float4*)(p + 4 * t);
    float4 v1 = *(const float4*)(p + 1024 + 4 * t);
    float vals[8] = {v0.x, v0.y, v0.z, v0.w, v1.x, v1.y, v1.z, v1.w};
    unsigned long long key[8];
#pragma unroll
    for (int i = 0; i < 8; i++) {
        int e = (i < 4) ? (4 * t + i) : (1024 + 4 * t + (i - 4));
        unsigned u = __float_as_uint(vals[i]);
        unsigned sk = (u & 0x80000000u) ? ~u : (u | 0x80000000u);
        key[i] = ((unsigned long long)sk << 11) | (unsigned)(2047 - e);
    }
    __shared__ int s_cnt;
    __shared__ int s_red[4];
    __shared__ unsigned long long s_cand[256];
    const int lane = t & 63, wv = t >> 6;

    // N(0,1) quantile ~1.76 -> E[survivors] ~ 80, sigma ~ 9: always in [32,256]
    unsigned thr0 = __float_as_uint(1.76f) | 0x80000000u;
    unsigned long long T = ((unsigned long long)thr0 << 11) | 2047ull;

    if (t == 0) s_cnt = 0;
    __syncthreads();
#pragma unroll
    for (int i = 0; i < 8; i++) {
        if (key[i] > T) {
            int pos = atomicAdd(&s_cnt, 1);
            if (pos < 256) s_cand[pos] = key[i];
        }
    }
    __syncthreads();

    if (s_cnt < TOPK || s_cnt > 256) {
        // rare fallback: bisect threshold until count in range, recompact
        unsigned long long lo = 0, hi = ~0ull;
        if (s_cnt > 256) lo = T; else hi = T;
        T = lo + ((hi - lo) >> 1);
        for (int it = 0; it < 40; ++it) {
            int c = 0;
#pragma unroll
            for (int i = 0; i < 8; i++) c += (key[i] > T) ? 1 : 0;
            for (int off = 32; off; off >>= 1) c += __shfl_down(c, off, 64);
            if (lane == 0) s_red[wv] = c;
            __syncthreads();
            int tot = s_red[0] + s_red[1] + s_red[2] + s_red[3];
            if (tot >= TOPK && tot <= 256) break;
            if (tot > 256) lo = T; else hi = T;
            T = lo + ((hi - lo) >> 1);
            __syncthreads();
        }
        if (t == 0) s_cnt = 0;
        __syncthreads();
#pragma unroll
        for (int i = 0; i < 8; i++) {
            if (key[i] > T) {
                int pos = atomicAdd(&s_cnt, 1);
                if (pos < 256) s_cand[pos] = key[i];
            }
        }
        __syncthreads();
    }

    const int C = s_cnt < 256 ? s_cnt : 256;
    // parallel rank select: candidate t's rank = #{j: key_j > key_t}
    if (t < C) {
        unsigned long long mk = s_cand[t];
        int rank = 0;
        for (int j = 0; j < C; ++j)
            rank += (s_cand[j] > mk) ? 1 : 0;   // broadcast LDS read, conflict-free
        if (rank < TOPK)
            idx_out[(size_t)row * TOPK + rank] = 2047 - (int)(mk & 2047ull);
    }
}

// ------------------------------------------------------- K2: softmax stats
// fp16 MFMA (not bf16): eps*Z dominates the renorm denominator, so Z's
// relative error is a per-(head,row) output scale that LN does NOT cancel.
// bf16 gave absmax 0.31; fp16 gives 0.0625 (threshold 0.246).
// Split-K: 2 blocks per Q-tile (half the keys each) -> 512 blocks = 2/CU.
typedef float f32x4 __attribute__((ext_vector_type(4)));
typedef _Float16 f16x8 __attribute__((ext_vector_type(8)));
typedef _Float16 f16x4 __attribute__((ext_vector_type(4)));

#define KPAD 136   // 128 + 8 halves pad: breaks LDS bank conflicts, keeps 16B align

__global__ __launch_bounds__(256) void stats_kernel(const float* __restrict__ q,
                                                    const float* __restrict__ k,
                                                    float* __restrict__ ws_m,
                                                    float* __restrict__ ws_l) {
    __shared__ __align__(16) _Float16 Qs[128 * KPAD];
    __shared__ __align__(16) _Float16 Ks[128 * KPAD];
    const int blk = blockIdx.x & 255;     // 256 tiles
    const int half = blockIdx.x >> 8;     // 0/1: key range halves
    const int bh = blk >> 4;              // 0..15
    const int qt = blk & 15;
    const int b = bh >> 3, h = bh & 7;
    const int t = threadIdx.x;
    const int wv = t >> 6, lane = t & 63;
    const int l16 = lane & 15, quad = lane >> 4;

    const float* qbase = q + ((size_t)(b * SS + qt * 128) * DD + h * HD);
#pragma unroll
    for (int i = 0; i < 16; ++i) {
        int fi = t + 256 * i;            // float4 index
        int r = fi >> 5, c4 = fi & 31;
        float4 f = *(const float4*)(qbase + (size_t)r * DD + c4 * 4);
        *(f16x4*)&Qs[r * KPAD + c4 * 4] =
            (f16x4){(_Float16)f.x, (_Float16)f.y, (_Float16)f.z, (_Float16)f.w};
    }
    float mrun[2][4], lrun[2][4];
#pragma unroll
    for (int a = 0; a < 2; a++)
#pragma unroll
        for (int r2 = 0; r2 < 4; r2++) { mrun[a][r2] = -INFINITY; lrun[a][r2] = 0.f; }

    const float* kbase = k + ((size_t)(b * SS) * DD + h * HD);
    for (int kt = half * 8; kt < half * 8 + 8; ++kt) {
        __syncthreads();
#pragma unroll
        for (int i = 0; i < 16; ++i) {
            int fi = t + 256 * i;
            int r = fi >> 5, c4 = fi & 31;
            float4 f = *(const float4*)(kbase + (size_t)(kt * 128 + r) * DD + c4 * 4);
            *(f16x4*)&Ks[r * KPAD + c4 * 4] =
                (f16x4){(_Float16)f.x, (_Float16)f.y, (_Float16)f.z, (_Float16)f.w};
        }
        __syncthreads();
        f32x4 acc[2][8];
#pragma unroll
        for (int a = 0; a < 2; a++)
#pragma unroll
            for (int n = 0; n < 8; n++) acc[a][n] = (f32x4){0.f, 0.f, 0.f, 0.f};
#pragma unroll
        for (int ks = 0; ks < 4; ++ks) {
            f16x8 af[2], bfr[8];
#pragma unroll
            for (int a = 0; a < 2; a++)
                af[a] = *(const f16x8*)&Qs[(wv * 32 + a * 16 + l16) * KPAD + ks * 32 + quad * 8];
#pragma unroll
            for (int n = 0; n < 8; n++)
                bfr[n] = *(const f16x8*)&Ks[(n * 16 + l16) * KPAD + ks * 32 + quad * 8];
#pragma unroll
            for (int a = 0; a < 2; a++)
#pragma unroll
                for (int n = 0; n < 8; n++)
                    acc[a][n] = __builtin_amdgcn_mfma_f32_16x16x32_f16(af[a], bfr[n], acc[a][n], 0, 0, 0);
        }
        // online max / sumexp per row (row = wv*32 + a*16 + quad*4 + r2)
#pragma unroll
        for (int a = 0; a < 2; a++) {
#pragma unroll
            for (int r2 = 0; r2 < 4; r2++) {
                float tm = acc[a][0][r2];
#pragma unroll
                for (int n = 1; n < 8; n++) tm = fmaxf(tm, acc[a][n][r2]);
#pragma unroll
                for (int off = 1; off < 16; off <<= 1) tm = fmaxf(tm, __shfl_xor(tm, off, 64));
                float tl = 0.f;
#pragma unroll
                for (int n = 0; n < 8; n++) tl += __expf(acc[a][n][r2] - tm);
#pragma unroll
                for (int off = 1; off < 16; off <<= 1) tl += __shfl_xor(tl, off, 64);
                float mo = mrun[a][r2];
                float mn = fmaxf(mo, tm);
                lrun[a][r2] = lrun[a][r2] * __expf(mo - mn) + tl * __expf(tm - mn);
                mrun[a][r2] = mn;
            }
        }
    }
    if (l16 == 0) {
#pragma unroll
        for (int a = 0; a < 2; a++)
#pragma unroll
            for (int r2 = 0; r2 < 4; r2++) {
                int rrow = qt * 128 + wv * 32 + a * 16 + quad * 4 + r2;
                size_t g = (size_t)half * ROWS + (size_t)bh * SS + rrow;
                ws_m[g] = mrun[a][r2];
                ws_l[g] = lrun[a][r2];
            }
    }
}

// --------------------------------------------- K2b: gather scores + PV (fp32)
// XCD swizzle: bh = blockIdx & 15 -> XCD = blockIdx % 8 = bh % 8, so each
// XCD's 4MB L2 holds exactly its 2 heads' k+v slices (4 x 1MB).
__global__ __launch_bounds__(128) void attnout_kernel(const float* __restrict__ q,
                                                      const float* __restrict__ k,
                                                      const float* __restrict__ v,
                                                      const int* __restrict__ idx_ws,
                                                      const float* __restrict__ ws_m,
                                                      const float* __restrict__ ws_l,
                                                      float* __restrict__ out) {
    const int bh = blockIdx.x & 15;
    const int s = blockIdx.x >> 4;
    const int R = (bh << 11) | s;
    const int b = bh >> 3, h = bh & 7;
    const int t = threadIdx.x;
    __shared__ float q_l[128];
    __shared__ int idx_l[32];
    __shared__ float e_l[32];
    __shared__ float w_l[32];
    const float* qrow = q + ((size_t)(b * SS + s) * DD + h * HD);
    q_l[t] = qrow[t];
    if (t < 32) idx_l[t] = idx_ws[(size_t)R * TOPK + t];
    __syncthreads();
    // merge split-K partial stats
    const float m0 = ws_m[R], m1 = ws_m[(size_t)ROWS + R];
    const float l0 = ws_l[R], l1 = ws_l[(size_t)ROWS + R];
    const float m = fmaxf(m0, m1);
    const float Z = l0 * __expf(m0 - m) + l1 * __expf(m1 - m);
    const int l32 = t & 31, g = t >> 5;   // 4 groups of 32 lanes
    float4 q4 = *(const float4*)&q_l[l32 * 4];
    const float* kb = k + ((size_t)b * SS * DD + h * HD);
#pragma unroll
    for (int p = 0; p < 8; ++p) {
        int i = p * 4 + g;
        int ki = idx_l[i];
        float4 kv = *(const float4*)(kb + (size_t)ki * DD + l32 * 4);
        float d = q4.x * kv.x + q4.y * kv.y + q4.z * kv.z + q4.w * kv.w;
#pragma unroll
        for (int off = 1; off < 32; off <<= 1) d += __shfl_xor(d, off, 64);
        if (l32 == 0) e_l[i] = __expf(d - m);
    }
    __syncthreads();
    if (t < 32) {
        float e = e_l[t];
        float ssum = e;
#pragma unroll
        for (int off = 1; off < 32; off <<= 1) ssum += __shfl_xor(ssum, off, 64);
        float den = ssum + 1e-5f * Z;     // = S_sel + eps*Z  (exact renorm algebra)
        w_l[t] = e / den;
    }
    __syncthreads();
    const float* vb = v + ((size_t)b * SS * DD + h * HD);
    float accv = 0.f;
#pragma unroll 8
    for (int i = 0; i < 32; ++i) {
        accv += w_l[i] * vb[(size_t)idx_l[i] * DD + t];
    }
    out[((size_t)(b * SS + s) * DD) + h * HD + t] = accv;
}

// ----------------------------------------------------- K3: LayerNorm in-place
__global__ __launch_bounds__(256) void ln_kernel(float* __restrict__ out,
                                                 const float* __restrict__ gamma,
                                                 const float* __restrict__ beta) {
    const int row = blockIdx.x;   // B*S = 4096
    float* p = out + (size_t)row * DD;
    const int t = threadIdx.x;
    float x[4];
#pragma unroll
    for (int i = 0; i < 4; i++) x[i] = p[t + 256 * i];
    float sum = x[0] + x[1] + x[2] + x[3];
    __shared__ float red[4];
    const int lane = t & 63, wv = t >> 6;
    for (int off = 32; off; off >>= 1) sum += __shfl_down(sum, off, 64);
    if (lane == 0) red[wv] = sum;
    __syncthreads();
    float mean = (red[0] + red[1] + red[2] + red[3]) * (1.f / DD);
    __syncthreads();
    float vs = 0.f;
#pragma unroll
    for (int i = 0; i < 4; i++) { float d = x[i] - mean; vs += d * d; }
    for (int off = 32; off; off >>= 1) vs += __shfl_down(vs, off, 64);
    if (lane == 0) red[wv] = vs;
    __syncthreads();
    float var = (red[0] + red[1] + red[2] + red[3]) * (1.f / DD);
    float inv = rsqrtf(var + 1e-5f);
#pragma unroll
    for (int i = 0; i < 4; i++) {
        int c = t + 256 * i;
        p[c] = (x[i] - mean) * inv * gamma[c] + beta[c];
    }
}

extern "C" void kernel_launch(void* const* d_in, const int* in_sizes, int n_in,
                              void* d_out, int out_size, void* d_ws, size_t ws_size,
                              hipStream_t stream) {
    const float* q = (const float*)d_in[0];
    const float* k = (const float*)d_in[1];
    const float* v = (const float*)d_in[2];
    const float* aw = (const float*)d_in[3];
    const float* gamma = (const float*)d_in[4];
    const float* beta = (const float*)d_in[5];
    float* out = (float*)d_out;

    int* idx_ws = (int*)d_ws;
    float* ws_m = (float*)((char*)d_ws + (size_t)ROWS * TOPK * sizeof(int));
    float* ws_l = ws_m + 2 * ROWS;   // 2 halves each

    hipLaunchKernelGGL(topk_kernel, dim3(ROWS), dim3(256), 0, stream, aw, idx_ws);
    hipLaunchKernelGGL(stats_kernel, dim3(512), dim3(256), 0, stream, q, k, ws_m, ws_l);
    hipLaunchKernelGGL(attnout_kernel, dim3(ROWS), dim3(128), 0, stream, q, k, v, idx_ws, ws_m, ws_l, out);
    hipLaunchKernelGGL(ln_kernel, dim3(BB * SS), dim3(256), 0, stream, out, gamma, beta);
}